// Round 10
// baseline (117.361 us; speedup 1.0000x reference)
//
#include <hip/hip_runtime.h>
#include <hip/hip_bf16.h>

#define NN 8192
#define DD 128

typedef short bf16x8 __attribute__((ext_vector_type(8)));
typedef float f32x4 __attribute__((ext_vector_type(4)));

// F16 stores bf16( sqrt(10*log2e) * f ), so MFMA output d = 10*log2e*s and
// e^{10 s} = exp2f(d). Shift-free softmax: |d| <= 14.43, row sums < 2e8, f32 ok.
// sum_l comes from IN-LOOP S/Sl accumulation (R8-proven math):
//   sum over pos logits = (lr ? Sl : S - Sl) * ln2
// -> no G class-sum buffer, no cnt1, nothing needs a memset dispatch.
// R8 ran this at __launch_bounds__(512,4) = 64-VGPR cap -> the 16 extra
// loop-carried accumulators spilled (8.5MB scratch writes, 118us). R9 proved
// (512,2) [cap 128] is safe for this geometry; live state here ~101 regs.
#define CSCALE  3.7982829f      /* sqrt(10*log2(e)) */
#define LN2     0.69314718056f

// ws layout (no memset: all zeroing done inside prep)
#define CTR_OFF  (NN * DD * 2)            /* int ctr[32]: col-block done ctr */
#define CTRC_OFF (CTR_OFF + 128)          /* float ctrC[32]: label-1 col count */
#define CTR2_OFF (CTRC_OFF + 128)         /* int: rowgroup-done counter */
#define ACC_OFF  (CTR2_OFF + 4)           /* float: loss accumulator */
#define EG_OFF   (CTRC_OFF + 256)         /* alignment slack; 4 x NN floats */
#define ELG_OFF  (EG_OFF + NN * 4)
#define SG_OFF   (ELG_OFF + NN * 4)
#define SLG_OFF  (SG_OFF + NN * 4)

// loss geometry (R7-proven core): 512 blocks = 32 row-groups x 16 col-groups
// block = 8 waves x 512 threads; wave owns 32 rows (2 m-tiles).
#define BROWS 256
#define BCOLS 512
#define TCOLS 32                 /* cols per LDS tile */
#define ITERS (BCOLS / TCOLS)    /* 16 */

__device__ __forceinline__ unsigned short f2bf(float x) {
    unsigned u = __float_as_uint(x);
    u = (u + 0x7FFFu + ((u >> 16) & 1u)) >> 16;   // RNE to bf16
    return (unsigned short)u;
}

// 256 blocks x 256 threads; 32 rows/block: fp32->bf16 (scaled) conversion +
// zero own Eg/Elg/Sg/Slg slice; block 0 zeroes control scalars (plain stores,
// consumed only by the next dispatch). No atomics, no LDS, no G, no labf.
__global__ __launch_bounds__(256) void prep_kernel(const float* __restrict__ F,
        unsigned short* __restrict__ F16,
        int* __restrict__ ctr, float* __restrict__ ctrC,
        int* __restrict__ ctr2, float* __restrict__ acc,
        float* __restrict__ Eg, float* __restrict__ Elg,
        float* __restrict__ Sg, float* __restrict__ Slg) {
    const int tid = threadIdx.x;
    const int wave = tid >> 6, lane = tid & 63;
    const int half = lane >> 5, l32 = lane & 31;   // half-wave per row
    const int rb = blockIdx.x * 32;
    if (tid < 32) {
        Eg[rb + tid] = 0.f; Elg[rb + tid] = 0.f;
        Sg[rb + tid] = 0.f; Slg[rb + tid] = 0.f;
    }
    if (blockIdx.x == 0) {
        if (tid < 32) { ctr[tid] = 0; ctrC[tid] = 0.f; }
        if (tid == 32) *ctr2 = 0;
        if (tid == 33) *acc = 0.f;
    }
    #pragma unroll
    for (int it = 0; it < 4; ++it) {
        const int row = rb + it * 8 + wave * 2 + half;
        const float4 f = *reinterpret_cast<const float4*>(F + row * DD + l32 * 4);
        ushort4 u;
        u.x = f2bf(CSCALE * f.x); u.y = f2bf(CSCALE * f.y);
        u.z = f2bf(CSCALE * f.z); u.w = f2bf(CSCALE * f.w);
        *reinterpret_cast<ushort4*>(F16 + row * DD + l32 * 4) = u;
    }
}

// 512 blocks x 512 threads (8 waves), 16 waves/CU. Block: 256 rows x 512
// cols; wave owns 32 rows (2 m-tiles). 32-col B tiles (8KB) double-buffered
// in LDS, XOR-swizzled; all 512 threads stage one 16B chunk/iter. R7 core +
// in-loop S/Sl accumulation. FUSED FINALIZE (R2/R4-proven gate): last
// col-block per rowgroup reads the 4 row stats + ctrC via coherent
// atomic-loads and computes per-row loss; 32nd finalize block writes out.
__global__ __launch_bounds__(512, 2) void loss_kernel(
        const unsigned short* __restrict__ F16, const int* __restrict__ labels,
        float* __restrict__ ctrC, int* __restrict__ ctr, int* __restrict__ ctr2,
        float* __restrict__ acc, float* __restrict__ Eg,
        float* __restrict__ Elg, float* __restrict__ Sg,
        float* __restrict__ Slg, float* __restrict__ out) {
    __shared__ unsigned short Bt[2][TCOLS * DD];   // 2 x 8KB
    __shared__ float Lab[BCOLS];
    __shared__ int sLast;
    __shared__ float wsum[8];
    const int tid  = threadIdx.x;
    const int wave = tid >> 6, lane = tid & 63;
    const int quad = lane >> 4, l16 = lane & 15;
    const int rg = blockIdx.x & 31;
    const int rb = rg * BROWS;
    const int cb = (blockIdx.x >> 5) * BCOLS;

    Lab[tid] = (float)labels[cb + tid];

    // A fragments (one-time gather): wave owns rows rw..rw+31 (2 m-tiles)
    const int rw = rb + wave * 32;
    bf16x8 a[2][4];
    #pragma unroll
    for (int m = 0; m < 2; m++)
        #pragma unroll
        for (int kb = 0; kb < 4; kb++)
            a[m][kb] = *reinterpret_cast<const bf16x8*>(
                F16 + (rw + m * 16 + l16) * DD + kb * 32 + quad * 8);

    // cooperative staging map: thread -> (col = tid>>4 in tile, chunk = tid&15)
    const int scol = tid >> 4;          // 0..31
    const int sc   = tid & 15;          // k-chunk (8 bf16 = 16B)
    const unsigned short* sbase = F16 + (cb + scol) * DD + sc * 8;
    const int sdst = sc * (TCOLS * 8) + (((scol ^ sc) & 31) * 8);

    // stage tile 0
    *reinterpret_cast<bf16x8*>(&Bt[0][sdst]) =
        *reinterpret_cast<const bf16x8*>(sbase);

    float accE[2][4] = {}, accEl[2][4] = {};
    float accS[2][4] = {}, accSl[2][4] = {};
    __syncthreads();

    // per-rowgroup label-1 column count: each of 8 waves sums its 64-col
    // slice; 8 waves x 16 col-blocks cover all 8192 cols exactly once.
    {
        float cc = Lab[wave * 64 + lane];
        #pragma unroll
        for (int off = 1; off < 64; off <<= 1) cc += __shfl_xor(cc, off);
        if (lane == 0) atomicAdd(&ctrC[rg], cc);
    }

    for (int it = 0; it < ITERS; ++it) {
        const int cur = it & 1;
        const int itn = (it + 1) & (ITERS - 1);   // wrap: last prefetch harmless
        const bf16x8 vn = *reinterpret_cast<const bf16x8*>(sbase + itn * TCOLS * DD);

        #pragma unroll
        for (int g = 0; g < 2; ++g) {
            bf16x8 bfr[4];
            #pragma unroll
            for (int kb = 0; kb < 4; kb++) {
                const int cr = kb * 4 + quad;
                const int col = g * 16 + l16;
                bfr[kb] = *reinterpret_cast<const bf16x8*>(
                    &Bt[cur][cr * (TCOLS * 8) + (((col ^ cr) & 31) * 8)]);
            }
            f32x4 d0 = {0.f, 0.f, 0.f, 0.f}, d1 = {0.f, 0.f, 0.f, 0.f};
            #pragma unroll
            for (int kb = 0; kb < 4; kb++) {
                d0 = __builtin_amdgcn_mfma_f32_16x16x32_bf16(a[0][kb], bfr[kb], d0, 0, 0, 0);
                d1 = __builtin_amdgcn_mfma_f32_16x16x32_bf16(a[1][kb], bfr[kb], d1, 0, 0, 0);
            }
            const float lc = Lab[it * TCOLS + g * 16 + l16];
            #pragma unroll
            for (int r = 0; r < 4; r++) {
                const float e0 = exp2f(d0[r]);
                accE[0][r] += e0; accEl[0][r] = fmaf(lc, e0, accEl[0][r]);
                accS[0][r] += d0[r]; accSl[0][r] = fmaf(lc, d0[r], accSl[0][r]);
                const float e1 = exp2f(d1[r]);
                accE[1][r] += e1; accEl[1][r] = fmaf(lc, e1, accEl[1][r]);
                accS[1][r] += d1[r]; accSl[1][r] = fmaf(lc, d1[r], accSl[1][r]);
            }
        }

        *reinterpret_cast<bf16x8*>(&Bt[cur ^ 1][sdst]) = vn;
        __syncthreads();
    }

    // 16-lane row reduce, then one global atomic per (row, stat)
    #pragma unroll
    for (int m = 0; m < 2; m++) {
        #pragma unroll
        for (int r = 0; r < 4; r++) {
            float e = accE[m][r], el = accEl[m][r];
            float s = accS[m][r], sl = accSl[m][r];
            #pragma unroll
            for (int off = 1; off < 16; off <<= 1) {
                e  += __shfl_xor(e,  off);
                el += __shfl_xor(el, off);
                s  += __shfl_xor(s,  off);
                sl += __shfl_xor(sl, off);
            }
            if (l16 == 0) {
                const int row = rw + m * 16 + quad * 4 + r;
                atomicAdd(&Eg[row], e);
                atomicAdd(&Elg[row], el);
                atomicAdd(&Sg[row], s);
                atomicAdd(&Slg[row], sl);
            }
        }
    }

    // ---- fused finalize: am I the last col-block of my row-group? ----
    __syncthreads();   // drains vmcnt: all this block's atomics are complete
    if (tid == 0) sLast = (atomicAdd(&ctr[rg], 1) == 15);
    __syncthreads();
    if (!sLast) return;   // whole block exits together (no divergent barrier)

    float li = 0.f;
    if (tid < 256) {
        const int row = rb + tid;
        const int lr  = labels[row];
        const float E  = atomicAdd(&Eg[row], 0.f);    // coherent atomic-loads
        const float El = atomicAdd(&Elg[row], 0.f);
        const float S  = atomicAdd(&Sg[row], 0.f);
        const float Sl = atomicAdd(&Slg[row], 0.f);
        const float c1f = atomicAdd(&ctrC[rg], 0.f);  // complete: each block's
                                                      // ctrC add preceded its ctr add
        const float Epos = lr ? El : (E - El);        // pos exp-sum (incl diag)
        const float Si   = E - Epos;                  // neg exp-sum
        const float cntp1 = lr ? c1f : ((float)NN - c1f);
        const float cntm  = cntp1 - 1.f;
        const float sum_l   = (lr ? Sl : (S - Sl)) * LN2;  // sum over pos logits
        const float sum_log = cntp1 * __logf(Si) + Epos / Si;
        li = -(10.f / 7.f) * (sum_l - sum_log) / cntm;
    }
    #pragma unroll
    for (int off = 1; off < 64; off <<= 1) li += __shfl_xor(li, off);
    if ((tid & 63) == 0) wsum[tid >> 6] = li;
    __syncthreads();
    if (tid == 0) {
        const float s = ((wsum[0] + wsum[1]) + (wsum[2] + wsum[3]))
                      + ((wsum[4] + wsum[5]) + (wsum[6] + wsum[7]));
        atomicAdd(acc, s * (1.0f / NN));
        __threadfence();   // order acc-add before ctr2-add (32 blocks only)
        if (atomicAdd(ctr2, 1) == 31) out[0] = atomicAdd(acc, 0.f);
    }
}

extern "C" void kernel_launch(void* const* d_in, const int* in_sizes, int n_in,
                              void* d_out, int out_size, void* d_ws, size_t ws_size,
                              hipStream_t stream) {
    const float* F      = (const float*)d_in[0];
    const int*   labels = (const int*)d_in[1];
    float*       out    = (float*)d_out;
    char*        ws     = (char*)d_ws;
    unsigned short* F16 = (unsigned short*)ws;
    int*         ctr    = (int*)(ws + CTR_OFF);
    float*       ctrC   = (float*)(ws + CTRC_OFF);
    int*         ctr2   = (int*)(ws + CTR2_OFF);
    float*       acc    = (float*)(ws + ACC_OFF);
    float*       Eg     = (float*)(ws + EG_OFF);
    float*       Elg    = (float*)(ws + ELG_OFF);
    float*       Sg     = (float*)(ws + SG_OFF);
    float*       Slg    = (float*)(ws + SLG_OFF);

    // NO memset: prep zeroes stat slices; prep block 0 zeroes control scalars.
    prep_kernel<<<NN / 32, 256, 0, stream>>>(F, F16, ctr, ctrC, ctr2, acc,
                                             Eg, Elg, Sg, Slg);
    loss_kernel<<<512, 512, 0, stream>>>(F16, labels, ctrC, ctr, ctr2, acc,
                                         Eg, Elg, Sg, Slg, out);
}

// Round 11
// 115.621 us; speedup vs baseline: 1.0151x; 1.0151x over previous
//
#include <hip/hip_runtime.h>
#include <hip/hip_bf16.h>

#define NN 8192
#define DD 128

typedef short bf16x8 __attribute__((ext_vector_type(8)));
typedef float f32x4 __attribute__((ext_vector_type(4)));

// F16 stores bf16( sqrt(10*log2e) * f ), so MFMA output d = 10*log2e*s and
// e^{10 s} = exp2f(d). Shift-free softmax: |d| <= 14.43, row sums < 2e8, f32 ok.
// sum_l via IN-LOOP S/Sl accumulation (math proven R8/R10, absmax 0.0):
//   sum over pos logits = (lr ? Sl : S - Sl) * ln2
// -> no G buffer, no cnt1, no memset dispatch.
// REGISTER GEOMETRY (hard-won): 512-thread blocks are capped at 64 VGPRs by
// hipcc regardless of launch_bounds arg2 (R8/R10: 8.5MB scratch, 66us loss).
// Only 256-thread blocks at (256,2) reach a 128 cap (R4/R5). So the S/Sl
// variant runs here as 256-thread blocks: 4 waves x 32 rows = 128x512 tile,
// grid 64 rowgroups x 16 colgroups = 1024 blocks, 4 blocks/CU = 16 waves/CU.
// Live state ~95 regs (a[2][4]=32 + 4 acc sets=32 + staging) <= 128.
#define CSCALE  3.7982829f      /* sqrt(10*log2(e)) */
#define LN2     0.69314718056f

// ws layout (no memset: all zeroing done inside prep)
#define CTR_OFF  (NN * DD * 2)            /* int ctr[64]: col-block done ctr */
#define CTRC_OFF (CTR_OFF + 256)          /* float ctrC[64]: label-1 col count */
#define CTR2_OFF (CTRC_OFF + 256)         /* int: rowgroup-done counter */
#define ACC_OFF  (CTR2_OFF + 4)           /* float: loss accumulator */
#define EG_OFF   (CTRC_OFF + 512)         /* alignment slack; 4 x NN floats */
#define ELG_OFF  (EG_OFF + NN * 4)
#define SG_OFF   (ELG_OFF + NN * 4)
#define SLG_OFF  (SG_OFF + NN * 4)

// loss geometry: 1024 blocks = 64 row-groups x 16 col-groups
// block = 4 waves x 256 threads; wave owns 32 rows (2 m-tiles); 128x512 tile
#define BROWS 128
#define BCOLS 512
#define TCOLS 32                 /* cols per LDS tile */
#define ITERS (BCOLS / TCOLS)    /* 16 */
#define RGRPS (NN / BROWS)       /* 64 */
#define CGRPS (NN / BCOLS)       /* 16 */

__device__ __forceinline__ unsigned short f2bf(float x) {
    unsigned u = __float_as_uint(x);
    u = (u + 0x7FFFu + ((u >> 16) & 1u)) >> 16;   // RNE to bf16
    return (unsigned short)u;
}

// 256 blocks x 256 threads; 32 rows/block: fp32->bf16 (scaled) conversion +
// zero own Eg/Elg/Sg/Slg slice; block 0 zeroes control scalars (plain stores,
// consumed only by the next dispatch — R5/R8-proven pattern).
__global__ __launch_bounds__(256) void prep_kernel(const float* __restrict__ F,
        unsigned short* __restrict__ F16,
        int* __restrict__ ctr, float* __restrict__ ctrC,
        int* __restrict__ ctr2, float* __restrict__ acc,
        float* __restrict__ Eg, float* __restrict__ Elg,
        float* __restrict__ Sg, float* __restrict__ Slg) {
    const int tid = threadIdx.x;
    const int wave = tid >> 6, lane = tid & 63;
    const int half = lane >> 5, l32 = lane & 31;   // half-wave per row
    const int rb = blockIdx.x * 32;
    if (tid < 32) {
        Eg[rb + tid] = 0.f; Elg[rb + tid] = 0.f;
        Sg[rb + tid] = 0.f; Slg[rb + tid] = 0.f;
    }
    if (blockIdx.x == 0) {
        if (tid < 64) { ctr[tid] = 0; ctrC[tid] = 0.f; }
        if (tid == 64) *ctr2 = 0;
        if (tid == 65) *acc = 0.f;
    }
    #pragma unroll
    for (int it = 0; it < 4; ++it) {
        const int row = rb + it * 8 + wave * 2 + half;
        const float4 f = *reinterpret_cast<const float4*>(F + row * DD + l32 * 4);
        ushort4 u;
        u.x = f2bf(CSCALE * f.x); u.y = f2bf(CSCALE * f.y);
        u.z = f2bf(CSCALE * f.z); u.w = f2bf(CSCALE * f.w);
        *reinterpret_cast<ushort4*>(F16 + row * DD + l32 * 4) = u;
    }
}

// 1024 blocks x 256 threads (4 waves), 4 blocks/CU = 16 waves/CU. Block:
// 128 rows x 512 cols; wave owns 32 rows (2 m-tiles). 32-col B tiles (8KB)
// double-buffered in LDS, XOR-swizzled; 256 threads stage 2 x 16B chunks/iter
// (R1-proven map). In-loop E/El/S/Sl accumulation. FUSED FINALIZE
// (R2/R4-proven gate): last col-block per rowgroup reads the 4 row stats +
// ctrC via coherent atomic-loads, computes per-row loss for its 128 rows;
// 64th finalize block writes out.
__global__ __launch_bounds__(256, 2) void loss_kernel(
        const unsigned short* __restrict__ F16, const int* __restrict__ labels,
        float* __restrict__ ctrC, int* __restrict__ ctr, int* __restrict__ ctr2,
        float* __restrict__ acc, float* __restrict__ Eg,
        float* __restrict__ Elg, float* __restrict__ Sg,
        float* __restrict__ Slg, float* __restrict__ out) {
    __shared__ unsigned short Bt[2][TCOLS * DD];   // 2 x 8KB
    __shared__ float Lab[BCOLS];
    __shared__ int sLast;
    __shared__ float wsum[4];
    const int tid  = threadIdx.x;
    const int wave = tid >> 6, lane = tid & 63;
    const int quad = lane >> 4, l16 = lane & 15;
    const int rg = blockIdx.x & (RGRPS - 1);
    const int rb = rg * BROWS;
    const int cb = (blockIdx.x >> 6) * BCOLS;

    Lab[tid]       = (float)labels[cb + tid];
    Lab[tid + 256] = (float)labels[cb + tid + 256];

    // A fragments (one-time gather): wave owns rows rw..rw+31 (2 m-tiles)
    const int rw = rb + wave * 32;
    bf16x8 a[2][4];
    #pragma unroll
    for (int m = 0; m < 2; m++)
        #pragma unroll
        for (int kb = 0; kb < 4; kb++)
            a[m][kb] = *reinterpret_cast<const bf16x8*>(
                F16 + (rw + m * 16 + l16) * DD + kb * 32 + quad * 8);

    // cooperative staging map (R1-proven): col = tid>>3, chunks (tid&7)*2, +1
    const int scol = tid >> 3;           // 0..31
    const int sc0  = (tid & 7) * 2;      // k-chunk pair (each 8 bf16 = 16B)
    const unsigned short* sbase = F16 + (cb + scol) * DD + sc0 * 8;
    const int sdst0 = sc0 * (TCOLS * 8) + (((scol ^ sc0) & 31) * 8);
    const int sdst1 = (sc0 + 1) * (TCOLS * 8) + (((scol ^ (sc0 + 1)) & 31) * 8);

    // stage tile 0
    *reinterpret_cast<bf16x8*>(&Bt[0][sdst0]) =
        *reinterpret_cast<const bf16x8*>(sbase);
    *reinterpret_cast<bf16x8*>(&Bt[0][sdst1]) =
        *reinterpret_cast<const bf16x8*>(sbase + 8);

    float accE[2][4] = {}, accEl[2][4] = {};
    float accS[2][4] = {}, accSl[2][4] = {};
    __syncthreads();

    // per-rowgroup label-1 column count: each of 4 waves sums a distinct
    // 128-col slice; 4 waves x 16 col-blocks cover all 8192 cols once.
    {
        float cc = Lab[wave * 128 + lane] + Lab[wave * 128 + 64 + lane];
        #pragma unroll
        for (int off = 1; off < 64; off <<= 1) cc += __shfl_xor(cc, off);
        if (lane == 0) atomicAdd(&ctrC[rg], cc);
    }

    for (int it = 0; it < ITERS; ++it) {
        const int cur = it & 1;
        const int itn = (it + 1) & (ITERS - 1);   // wrap: last prefetch harmless
        const bf16x8 vn0 = *reinterpret_cast<const bf16x8*>(sbase + itn * TCOLS * DD);
        const bf16x8 vn1 = *reinterpret_cast<const bf16x8*>(sbase + itn * TCOLS * DD + 8);

        #pragma unroll
        for (int g = 0; g < 2; ++g) {
            bf16x8 bfr[4];
            #pragma unroll
            for (int kb = 0; kb < 4; kb++) {
                const int cr = kb * 4 + quad;
                const int col = g * 16 + l16;
                bfr[kb] = *reinterpret_cast<const bf16x8*>(
                    &Bt[cur][cr * (TCOLS * 8) + (((col ^ cr) & 31) * 8)]);
            }
            f32x4 d0 = {0.f, 0.f, 0.f, 0.f}, d1 = {0.f, 0.f, 0.f, 0.f};
            #pragma unroll
            for (int kb = 0; kb < 4; kb++) {
                d0 = __builtin_amdgcn_mfma_f32_16x16x32_bf16(a[0][kb], bfr[kb], d0, 0, 0, 0);
                d1 = __builtin_amdgcn_mfma_f32_16x16x32_bf16(a[1][kb], bfr[kb], d1, 0, 0, 0);
            }
            const float lc = Lab[it * TCOLS + g * 16 + l16];
            #pragma unroll
            for (int r = 0; r < 4; r++) {
                const float e0 = exp2f(d0[r]);
                accE[0][r] += e0; accEl[0][r] = fmaf(lc, e0, accEl[0][r]);
                accS[0][r] += d0[r]; accSl[0][r] = fmaf(lc, d0[r], accSl[0][r]);
                const float e1 = exp2f(d1[r]);
                accE[1][r] += e1; accEl[1][r] = fmaf(lc, e1, accEl[1][r]);
                accS[1][r] += d1[r]; accSl[1][r] = fmaf(lc, d1[r], accSl[1][r]);
            }
        }

        *reinterpret_cast<bf16x8*>(&Bt[cur ^ 1][sdst0]) = vn0;
        *reinterpret_cast<bf16x8*>(&Bt[cur ^ 1][sdst1]) = vn1;
        __syncthreads();
    }

    // 16-lane row reduce, then one global atomic per (row, stat)
    #pragma unroll
    for (int m = 0; m < 2; m++) {
        #pragma unroll
        for (int r = 0; r < 4; r++) {
            float e = accE[m][r], el = accEl[m][r];
            float s = accS[m][r], sl = accSl[m][r];
            #pragma unroll
            for (int off = 1; off < 16; off <<= 1) {
                e  += __shfl_xor(e,  off);
                el += __shfl_xor(el, off);
                s  += __shfl_xor(s,  off);
                sl += __shfl_xor(sl, off);
            }
            if (l16 == 0) {
                const int row = rw + m * 16 + quad * 4 + r;
                atomicAdd(&Eg[row], e);
                atomicAdd(&Elg[row], el);
                atomicAdd(&Sg[row], s);
                atomicAdd(&Slg[row], sl);
            }
        }
    }

    // ---- fused finalize: am I the last col-block of my row-group? ----
    __syncthreads();   // drains vmcnt: all this block's atomics are complete
    if (tid == 0) sLast = (atomicAdd(&ctr[rg], 1) == CGRPS - 1);
    __syncthreads();
    if (!sLast) return;   // whole block exits together (no divergent barrier)

    float li = 0.f;
    if (tid < BROWS) {
        const int row = rb + tid;
        const int lr  = labels[row];
        const float E  = atomicAdd(&Eg[row], 0.f);    // coherent atomic-loads
        const float El = atomicAdd(&Elg[row], 0.f);
        const float S  = atomicAdd(&Sg[row], 0.f);
        const float Sl = atomicAdd(&Slg[row], 0.f);
        const float c1f = atomicAdd(&ctrC[rg], 0.f);  // complete: each block's
                                                      // ctrC add preceded its ctr add
        const float Epos = lr ? El : (E - El);        // pos exp-sum (incl diag)
        const float Si   = E - Epos;                  // neg exp-sum
        const float cntp1 = lr ? c1f : ((float)NN - c1f);
        const float cntm  = cntp1 - 1.f;
        const float sum_l   = (lr ? Sl : (S - Sl)) * LN2;  // sum over pos logits
        const float sum_log = cntp1 * __logf(Si) + Epos / Si;
        li = -(10.f / 7.f) * (sum_l - sum_log) / cntm;
    }
    #pragma unroll
    for (int off = 1; off < 64; off <<= 1) li += __shfl_xor(li, off);
    if ((tid & 63) == 0) wsum[tid >> 6] = li;
    __syncthreads();
    if (tid == 0) {
        atomicAdd(acc, ((wsum[0] + wsum[1]) + (wsum[2] + wsum[3])) * (1.0f / NN));
        __threadfence();   // order acc-add before ctr2-add (64 blocks only)
        if (atomicAdd(ctr2, 1) == RGRPS - 1) out[0] = atomicAdd(acc, 0.f);
    }
}

extern "C" void kernel_launch(void* const* d_in, const int* in_sizes, int n_in,
                              void* d_out, int out_size, void* d_ws, size_t ws_size,
                              hipStream_t stream) {
    const float* F      = (const float*)d_in[0];
    const int*   labels = (const int*)d_in[1];
    float*       out    = (float*)d_out;
    char*        ws     = (char*)d_ws;
    unsigned short* F16 = (unsigned short*)ws;
    int*         ctr    = (int*)(ws + CTR_OFF);
    float*       ctrC   = (float*)(ws + CTRC_OFF);
    int*         ctr2   = (int*)(ws + CTR2_OFF);
    float*       acc    = (float*)(ws + ACC_OFF);
    float*       Eg     = (float*)(ws + EG_OFF);
    float*       Elg    = (float*)(ws + ELG_OFF);
    float*       Sg     = (float*)(ws + SG_OFF);
    float*       Slg    = (float*)(ws + SLG_OFF);

    // NO memset: prep zeroes stat slices; prep block 0 zeroes control scalars.
    prep_kernel<<<NN / 32, 256, 0, stream>>>(F, F16, ctr, ctrC, ctr2, acc,
                                             Eg, Elg, Sg, Slg);
    loss_kernel<<<RGRPS * CGRPS, 256, 0, stream>>>(F16, labels, ctrC, ctr, ctr2,
                                                   acc, Eg, Elg, Sg, Slg, out);
}

// Round 12
// 100.462 us; speedup vs baseline: 1.1682x; 1.1509x over previous
//
#include <hip/hip_runtime.h>
#include <hip/hip_bf16.h>

#define NN 8192
#define DD 128

typedef short bf16x8 __attribute__((ext_vector_type(8)));
typedef float f32x4 __attribute__((ext_vector_type(4)));

// F16 stores bf16( sqrt(10*log2e) * f ), so MFMA output = 10*log2e*s and
// e^{10 s} = exp2f(d) with no per-element fma. Shift-free softmax is safe:
// |d| <= 14.43 -> exp2 in [2^-14.4, 2^14.4], row sums < 2e8, fine in f32.
#define CSCALE  3.7982829f      /* sqrt(10*log2(e)) */
#define SLSCALE 2.6327684f      /* 10 / CSCALE = sqrt(10*ln2) */

// ws layout (R2-proven)
#define LABF_OFF (NN * DD * 2)
#define G_OFF    (LABF_OFF + NN * 4)     /* 256 floats: [g1(128) | gtot(128)] */
#define CNT_OFF  (G_OFF + 1024)          /* int cnt1 */
#define CTR2_OFF (G_OFF + 1028)          /* int: rowgroup-done counter */
#define ACC_OFF  (G_OFF + 1032)          /* float: loss accumulator */
#define CTR_OFF  (G_OFF + 1152)          /* int[32]: per-rowgroup col-block ctr */
#define EG_OFF   (G_OFF + 1280)
#define ELG_OFF  (EG_OFF + NN * 4)

// loss geometry (R7/R9-proven core): 512 blocks = 32 row-groups x 16
// col-groups; block = 8 waves x 512 threads; wave owns 32 rows (2 m-tiles).
// SESSION FINDINGS (hard-won, do not revisit):
//  - 512-thread blocks allocate 64 VGPRs regardless of launch_bounds arg2;
//    this core's ~85 live values fit via AGPRs -> no spill (R9 == R7 perf).
//  - Any +16 loop-carried VALU accumulators (S/Sl variant) -> scratch path,
//    6x slower loss in EVERY geometry (R8/R10/R11).
//  - 64-row waves, in-kernel fp32 convert, coop-launch, Gp-partial tails,
//    BCOLS=256: all regressed (R1/R3/R4/R5/R6).
//  - Loss core is LDS-read-bound (~8 B/elem, ~10.5us); fills (84us) are at
//    the HBM roofline and belong to the harness.
#define BROWS 256
#define BCOLS 512
#define TCOLS 32                 /* cols per LDS tile */
#define ITERS (BCOLS / TCOLS)    /* 16 */

__device__ __forceinline__ unsigned short f2bf(float x) {
    unsigned u = __float_as_uint(x);
    u = (u + 0x7FFFu + ((u >> 16) & 1u)) >> 16;   // RNE to bf16
    return (unsigned short)u;
}

// 256 blocks x 256 threads; 32 rows/block: fp32->bf16 (scaled), labf,
// class sums G (atomic, pre-zeroed by the single memset), label-1 count;
// zeroes this block's Eg/Elg slice. Byte-identical to R2/R7's prep.
__global__ __launch_bounds__(256) void prep_kernel(const float* __restrict__ F,
        const int* __restrict__ labels, unsigned short* __restrict__ F16,
        float* __restrict__ labf, float* __restrict__ G,
        int* __restrict__ cnt1, float* __restrict__ Eg, float* __restrict__ Elg) {
    __shared__ float sG[256];
    __shared__ int scnt;
    const int tid = threadIdx.x;
    sG[tid] = 0.f;
    if (tid == 0) scnt = 0;
    __syncthreads();
    const int wave = tid >> 6, lane = tid & 63;
    const int half = lane >> 5, l32 = lane & 31;   // half-wave per row
    const int rb = blockIdx.x * 32;
    if (tid < 32) { Eg[rb + tid] = 0.f; Elg[rb + tid] = 0.f; }
    int mycnt = 0;
    float g1a[4] = {0.f, 0.f, 0.f, 0.f}, gta[4] = {0.f, 0.f, 0.f, 0.f};
    #pragma unroll
    for (int it = 0; it < 4; ++it) {
        const int row = rb + it * 8 + wave * 2 + half;
        const int lab = labels[row];
        const float lf = (float)lab;
        const float4 f = *reinterpret_cast<const float4*>(F + row * DD + l32 * 4);
        ushort4 u;
        u.x = f2bf(CSCALE * f.x); u.y = f2bf(CSCALE * f.y);
        u.z = f2bf(CSCALE * f.z); u.w = f2bf(CSCALE * f.w);
        *reinterpret_cast<ushort4*>(F16 + row * DD + l32 * 4) = u;
        g1a[0] = fmaf(lf, f.x, g1a[0]); gta[0] += f.x;
        g1a[1] = fmaf(lf, f.y, g1a[1]); gta[1] += f.y;
        g1a[2] = fmaf(lf, f.z, g1a[2]); gta[2] += f.z;
        g1a[3] = fmaf(lf, f.w, g1a[3]); gta[3] += f.w;
        if (l32 == 0) {
            labf[row] = lf;
            mycnt += lab;
        }
    }
    #pragma unroll
    for (int j = 0; j < 4; ++j) {
        atomicAdd(&sG[l32 * 4 + j], g1a[j]);
        atomicAdd(&sG[128 + l32 * 4 + j], gta[j]);
    }
    if (l32 == 0 && mycnt) atomicAdd(&scnt, mycnt);
    __syncthreads();
    atomicAdd(&G[tid], sG[tid]);
    if (tid == 0) atomicAdd(cnt1, scnt);
}

// 512 blocks x 512 threads (8 waves), 16 waves/CU. Block: 256 rows x 512
// cols; wave owns 32 rows (2 m-tiles, a[2][4]=32 VGPRs). 32-col B tiles
// (8KB) double-buffered in LDS; all 512 threads stage one 16B chunk/iter
// (coalesced); XOR-swizzled LDS. R7 core at (512,2).
__global__ __launch_bounds__(512, 2) void loss_kernel(
        const unsigned short* __restrict__ F16, const float* __restrict__ labf,
        const int* __restrict__ labels, const float* __restrict__ G,
        const int* __restrict__ cnt1, float* __restrict__ Eg,
        float* __restrict__ Elg, int* __restrict__ ctr, int* __restrict__ ctr2,
        float* __restrict__ acc, float* __restrict__ out) {
    __shared__ unsigned short Bt[2][TCOLS * DD];   // 2 x 8KB
    __shared__ float Lab[BCOLS];                   // reused as G cache in tail
    __shared__ int sLast;
    __shared__ float wsum[8];
    const int tid  = threadIdx.x;
    const int wave = tid >> 6, lane = tid & 63;
    const int quad = lane >> 4, l16 = lane & 15;
    const int rg = blockIdx.x & 31;
    const int rb = rg * BROWS;
    const int cb = (blockIdx.x >> 5) * BCOLS;

    Lab[tid] = labf[cb + tid];

    // A fragments (one-time gather): wave owns rows rw..rw+31 (2 m-tiles)
    const int rw = rb + wave * 32;
    bf16x8 a[2][4];
    #pragma unroll
    for (int m = 0; m < 2; m++)
        #pragma unroll
        for (int kb = 0; kb < 4; kb++)
            a[m][kb] = *reinterpret_cast<const bf16x8*>(
                F16 + (rw + m * 16 + l16) * DD + kb * 32 + quad * 8);

    // cooperative staging map: thread -> (col = tid>>4 in tile, chunk = tid&15)
    const int scol = tid >> 4;          // 0..31
    const int sc   = tid & 15;          // k-chunk (8 bf16 = 16B)
    const unsigned short* sbase = F16 + (cb + scol) * DD + sc * 8;
    const int sdst = sc * (TCOLS * 8) + (((scol ^ sc) & 31) * 8);

    // stage tile 0
    *reinterpret_cast<bf16x8*>(&Bt[0][sdst]) =
        *reinterpret_cast<const bf16x8*>(sbase);

    float accE[2][4] = {}, accEl[2][4] = {};
    __syncthreads();

    for (int it = 0; it < ITERS; ++it) {
        const int cur = it & 1;
        const int itn = (it + 1) & (ITERS - 1);   // wrap: last prefetch harmless
        const bf16x8 vn = *reinterpret_cast<const bf16x8*>(sbase + itn * TCOLS * DD);

        #pragma unroll
        for (int g = 0; g < 2; ++g) {
            bf16x8 bfr[4];
            #pragma unroll
            for (int kb = 0; kb < 4; kb++) {
                const int cr = kb * 4 + quad;
                const int col = g * 16 + l16;
                bfr[kb] = *reinterpret_cast<const bf16x8*>(
                    &Bt[cur][cr * (TCOLS * 8) + (((col ^ cr) & 31) * 8)]);
            }
            f32x4 d0 = {0.f, 0.f, 0.f, 0.f}, d1 = {0.f, 0.f, 0.f, 0.f};
            #pragma unroll
            for (int kb = 0; kb < 4; kb++) {
                d0 = __builtin_amdgcn_mfma_f32_16x16x32_bf16(a[0][kb], bfr[kb], d0, 0, 0, 0);
                d1 = __builtin_amdgcn_mfma_f32_16x16x32_bf16(a[1][kb], bfr[kb], d1, 0, 0, 0);
            }
            const float lc = Lab[it * TCOLS + g * 16 + l16];
            #pragma unroll
            for (int r = 0; r < 4; r++) {
                const float e0 = exp2f(d0[r]);
                accE[0][r] += e0; accEl[0][r] = fmaf(lc, e0, accEl[0][r]);
                const float e1 = exp2f(d1[r]);
                accE[1][r] += e1; accEl[1][r] = fmaf(lc, e1, accEl[1][r]);
            }
        }

        *reinterpret_cast<bf16x8*>(&Bt[cur ^ 1][sdst]) = vn;
        __syncthreads();
    }

    // 16-lane row reduce, then one global atomic per (row, stat)
    #pragma unroll
    for (int m = 0; m < 2; m++) {
        #pragma unroll
        for (int r = 0; r < 4; r++) {
            float e = accE[m][r], el = accEl[m][r];
            #pragma unroll
            for (int off = 1; off < 16; off <<= 1) {
                e  += __shfl_xor(e,  off);
                el += __shfl_xor(el, off);
            }
            if (l16 == 0) {
                const int row = rw + m * 16 + quad * 4 + r;
                atomicAdd(&Eg[row], e);
                atomicAdd(&Elg[row], el);
            }
        }
    }

    // ---- fused finalize: am I the last col-block of my row-group? ----
    __syncthreads();   // drains vmcnt: all this block's atomics are complete
    if (tid == 0) sLast = (atomicAdd(&ctr[rg], 1) == 15);
    __syncthreads();
    if (!sLast) return;   // whole block exits together (no divergent barrier)

    if (tid < 256) Lab[tid] = G[tid];   // class sums from prep (prev dispatch)
    __syncthreads();

    float li = 0.f;
    if (tid < 256) {
        const int row = rb + tid;
        const int lr  = labels[row];
        const float E  = atomicAdd(&Eg[row], 0.f);    // coherent atomic-loads
        const float El = atomicAdd(&Elg[row], 0.f);
        float dot = 0.f;
        const unsigned short* fp = F16 + row * DD;
        #pragma unroll
        for (int k = 0; k < DD; k += 8) {
            const bf16x8 fv = *reinterpret_cast<const bf16x8*>(fp + k);
            #pragma unroll
            for (int j = 0; j < 8; j++) {
                const float fj = __uint_as_float(((unsigned)(unsigned short)fv[j]) << 16);
                const float g1 = Lab[k + j];
                const float gl = lr ? g1 : (Lab[128 + k + j] - g1);
                dot = fmaf(fj, gl, dot);
            }
        }
        const float Epos = lr ? El : (E - El);     // pos exp-sum (incl diag)
        const float Si   = E - Epos;               // neg exp-sum
        const int   c1   = *cnt1;
        const float cntp1 = (float)(lr ? c1 : (NN - c1));
        const float cntm  = cntp1 - 1.f;
        const float sum_l   = SLSCALE * dot;       // = 10 * (f_i . class_sum)
        const float sum_log = cntp1 * __logf(Si) + Epos / Si;
        li = -(10.f / 7.f) * (sum_l - sum_log) / cntm;
    }
    #pragma unroll
    for (int off = 1; off < 64; off <<= 1) li += __shfl_xor(li, off);
    if ((tid & 63) == 0) wsum[tid >> 6] = li;
    __syncthreads();
    if (tid == 0) {
        const float s = ((wsum[0] + wsum[1]) + (wsum[2] + wsum[3]))
                      + ((wsum[4] + wsum[5]) + (wsum[6] + wsum[7]));
        atomicAdd(acc, s * (1.0f / NN));
        __threadfence();   // order acc-add before ctr2-add (32 blocks only)
        if (atomicAdd(ctr2, 1) == 31) out[0] = atomicAdd(acc, 0.f);
    }
}

extern "C" void kernel_launch(void* const* d_in, const int* in_sizes, int n_in,
                              void* d_out, int out_size, void* d_ws, size_t ws_size,
                              hipStream_t stream) {
    const float* F      = (const float*)d_in[0];
    const int*   labels = (const int*)d_in[1];
    float*       out    = (float*)d_out;
    char*        ws     = (char*)d_ws;
    unsigned short* F16 = (unsigned short*)ws;
    float*       labf   = (float*)(ws + LABF_OFF);
    float*       G      = (float*)(ws + G_OFF);
    int*         cnt1   = (int*)(ws + CNT_OFF);
    int*         ctr2   = (int*)(ws + CTR2_OFF);
    float*       acc    = (float*)(ws + ACC_OFF);
    int*         ctr    = (int*)(ws + CTR_OFF);
    float*       Eg     = (float*)(ws + EG_OFF);
    float*       Elg    = (float*)(ws + ELG_OFF);

    // single tiny memset: G(1024) + cnt1 + ctr2 + acc + ctr[32] (pad incl.)
    hipMemsetAsync(ws + G_OFF, 0, 1280, stream);

    prep_kernel<<<NN / 32, 256, 0, stream>>>(F, labels, F16, labf, G, cnt1, Eg, Elg);
    loss_kernel<<<512, 512, 0, stream>>>(F16, labf, labels, G, cnt1,
                                         Eg, Elg, ctr, ctr2, acc, out);
}